// Round 8
// baseline (201.303 us; speedup 1.0000x reference)
//
#include <hip/hip_runtime.h>
#include <hip/hip_bf16.h>

// B=8, N=256, D=128, E=32, H=4, HD=32
// ws layout (float/u32 offsets)
#define OFF_WQT 0          // 16384 transposed wq  [k][d]
#define OFF_WKT 16384
#define OFF_WVT 32768
#define OFF_OWT 49152      // transposed out_w [k][d]
#define OFF_GWT 65536      // transposed gcn_w [k][d]
#define OFF_WKE 81920      // 4096: wk@edge_w, row-major [d][e]
#define OFF_WVET 86016     // 4096: (wv@edge_w)^T, [e][d]
#define OFF_KB  90112      // 128 f32
#define OFF_VB  90240      // 128 f32
#define OFF_SC  90368      // 8192: per-row per-head score const
#define OFF_QSP 98560      // 131072 u32: q/sqrt(HD) packed f16 pairs (64/row)
#define OFF_QEP 229632     // 131072 u32: qe packed f16 pairs
#define OFF_HG  360704     // 262144 f32: gcn branch output (incl gcn_b)
#define OFF_K0P 622848     // 131072 u32: K0 packed f16 (64/row)
#define OFF_V0P 753920     // 131072 u32: V0 packed f16
// total 885 Kf = 3.54 MB

// gfx950 builtins use the __fp16 ext-vector type (NOT _Float16)
using half2_t = __attribute__((ext_vector_type(2))) __fp16;

static __device__ __forceinline__ half2_t u2h(unsigned int u){
  union { unsigned int u; half2_t h; } x; x.u = u; return x.h;
}
static __device__ __forceinline__ unsigned int pkf16(float a, float b){
  union { half2_t h; unsigned int u; } x;
  x.h = __builtin_amdgcn_cvt_pkrtz(a, b);
  return x.u;
}
static __device__ __forceinline__ float fdot2(unsigned int a, unsigned int b, float c){
  return __builtin_amdgcn_fdot2(u2h(a), u2h(b), c, false);
}

// ---------------------------------------------------------------------------
// Kernel A (prep): 5 weight transposes + Wke / WveT + fused biases.
// ---------------------------------------------------------------------------
__global__ __launch_bounds__(256) void prep_kernel(
    const float* __restrict__ wq, const float* __restrict__ wk,
    const float* __restrict__ wv, const float* __restrict__ out_w,
    const float* __restrict__ gcn_w, const float* __restrict__ edge_w,
    const float* __restrict__ edge_b, const float* __restrict__ bk,
    const float* __restrict__ bv, float* __restrict__ ws)
{
  int blk = blockIdx.x, t = threadIdx.x;
  if (blk < 320) {
    int w = blk >> 6;
    int e0 = (blk & 63) * 256 + t;
    const float* src = (w==0) ? wq : (w==1) ? wk : (w==2) ? wv : (w==3) ? out_w : gcn_w;
    float* dst = ws + ((w==0) ? OFF_WQT : (w==1) ? OFF_WKT : (w==2) ? OFF_WVT
                      : (w==3) ? OFF_OWT : OFF_GWT);
    int k = e0 >> 7, d = e0 & 127;
    dst[e0] = src[d*128 + k];
  } else if (blk < 352) {
    int idx = blk - 320;
    int which = idx >> 4;                  // 0: Wke (row-major), 1: WveT (transposed)
    int e0 = (idx & 15) * 256 + t;
    int dd = e0 >> 5, e = e0 & 31;
    const float* W = which ? wv : wk;
    float acc = 0.f;
    #pragma unroll 4
    for (int k2 = 0; k2 < 128; ++k2) acc += W[dd*128+k2] * edge_w[k2*32+e];
    if (which) ws[OFF_WVET + e*128 + dd] = acc;
    else       ws[OFF_WKE + e0] = acc;
  } else {
    int dd = t & 127;
    const float* W  = (t < 128) ? wk : wv;
    const float* bb = (t < 128) ? bk : bv;
    float acc = bb[dd];
    #pragma unroll 4
    for (int k2 = 0; k2 < 128; ++k2) acc += W[dd*128+k2] * edge_b[k2];
    ws[((t < 128) ? OFF_KB : OFF_VB) + dd] = acc;
  }
}

// ---------------------------------------------------------------------------
// Kernel B (proj) v2, R8: 4 rows/block (was 2), grid 512 (was 1024).
// Halves per-row weight re-reads (L2 traffic 328 -> 164 MB) and halves the
// number of barrier-chain executions. Probe: if proj was the hidden ~40us
// in the stable 145us constant, this recovers most of it.
// ---------------------------------------------------------------------------
__global__ __launch_bounds__(256) void proj_kernel(
    const float* __restrict__ h, const float* __restrict__ adj,
    const float* __restrict__ bq, const float* __restrict__ gcn_b,
    float* __restrict__ ws)
{
  __shared__ float h_lds[4*128];
  __shared__ float adj_lds[4*256];
  __shared__ float p1[2][4][128];
  __shared__ float p2[2][4][128];
  __shared__ float p3[2][4][128];
  __shared__ float qrow[4*132];
  __shared__ float qe_l[4*132];
  __shared__ float dpart[2][4];
  __shared__ float ha_lds[4*132];

  int t = threadIdx.x;
  int d = t & 127, kh = t >> 7;
  int r0 = blockIdx.x * 4;
  int b  = r0 >> 8, n0 = r0 & 255;
  unsigned int* wsu = (unsigned int*)ws;

  if (t < 128) ((float4*)h_lds)[t] = ((const float4*)(h + (size_t)r0*128))[t];
  ((float4*)adj_lds)[t] = ((const float4*)(adj + (size_t)r0*256))[t];
  __syncthreads();

  // --- A: qkv matvecs over 4 rows, transposed weights (lane-d coalesced) ---
  {
    const float* wqT = ws + OFF_WQT;
    const float* wkT = ws + OFF_WKT;
    const float* wvT = ws + OFF_WVT;
    float aq[4]={0,0,0,0}, ak[4]={0,0,0,0}, av[4]={0,0,0,0};
    #pragma unroll 2
    for (int kk = 0; kk < 64; ++kk) {
      int k = kh*64 + kk;
      float qw = wqT[k*128+d], kw = wkT[k*128+d], vw = wvT[k*128+d];
      #pragma unroll
      for (int i = 0; i < 4; ++i) {
        float hv = h_lds[i*128+k];
        aq[i] += qw*hv; ak[i] += kw*hv; av[i] += vw*hv;
      }
    }
    #pragma unroll
    for (int i = 0; i < 4; ++i) {
      p1[kh][i][d]=aq[i]; p2[kh][i][d]=ak[i]; p3[kh][i][d]=av[i];
    }
  }
  __syncthreads();

  // --- B: qrow (f32 LDS) + K/V pack to global ---
  #pragma unroll
  for (int rep = 0; rep < 2; ++rep) {
    int idx = rep*256 + t, i = idx >> 7, dd = idx & 127;
    const float inv = 0.17677669529663687f;   // 1/sqrt(32)
    qrow[i*132 + dd] = (p1[0][i][dd] + p1[1][i][dd] + bq[dd]) * inv;
  }
  #pragma unroll
  for (int rep = 0; rep < 2; ++rep) {
    int idx = rep*256 + t;
    int which = idx >> 8, i = (idx >> 6) & 3, pr = idx & 63;
    if (which == 0) {
      float k0 = p2[0][i][2*pr] + p2[1][i][2*pr];
      float k1 = p2[0][i][2*pr+1] + p2[1][i][2*pr+1];
      wsu[OFF_K0P + (size_t)(r0+i)*64 + pr] = pkf16(k0, k1);
    } else {
      float v0 = p3[0][i][2*pr] + p3[1][i][2*pr];
      float v1 = p3[0][i][2*pr+1] + p3[1][i][2*pr+1];
      wsu[OFF_V0P + (size_t)(r0+i)*64 + pr] = pkf16(v0, v1);
    }
  }
  __syncthreads();   // qrow ready; p1..p3 free

  // --- C: qs-pack, qe compute, sc, GCN aggregation (4 rows) ---
  {
    int i = t >> 6, pr = t & 63;
    wsu[OFF_QSP + (size_t)(r0+i)*64 + pr] = pkf16(qrow[i*132 + 2*pr], qrow[i*132 + 2*pr+1]);
  }
  #pragma unroll
  for (int rep = 0; rep < 2; ++rep) {
    int idx = rep*256 + t, i = idx >> 7, he = idx & 127, hh = he >> 5, e = he & 31;
    float acc = 0.f;
    #pragma unroll 8
    for (int j = 0; j < 32; ++j)
      acc += ws[OFF_WKE + (hh*32 + j)*32 + e] * qrow[i*132 + hh*32 + j];
    qe_l[i*132 + he] = acc;
  }
  if (t < 16) {
    int i = t >> 2, hh = t & 3;
    float acc = 0.f;
    #pragma unroll 8
    for (int j = 0; j < 32; ++j)
      acc += qrow[i*132 + hh*32 + j] * ws[OFF_KB + hh*32 + j];
    ws[OFF_SC + (size_t)(r0+i)*4 + hh] = acc;
  }
  {
    float ag[4]={0,0,0,0}, dg[4]={0,0,0,0};
    #pragma unroll 2
    for (int mm = 0; mm < 128; ++mm) {
      int ml = kh*128 + mm;
      float hv = h[((size_t)b*256 + ml)*128 + d];
      #pragma unroll
      for (int i = 0; i < 4; ++i) {
        float a = adj_lds[i*256 + ml] + ((ml == n0 + i) ? 1.0f : 0.0f);
        ag[i] += a*hv; dg[i] += a;
      }
    }
    #pragma unroll
    for (int i = 0; i < 4; ++i) p1[kh][i][d] = ag[i];
    if (d == 0) {
      #pragma unroll
      for (int i = 0; i < 4; ++i) dpart[kh][i] = dg[i];
    }
  }
  __syncthreads();

  // --- D: qe-pack + ha ---
  {
    int i = t >> 6, pr = t & 63;
    wsu[OFF_QEP + (size_t)(r0+i)*64 + pr] = pkf16(qe_l[i*132 + 2*pr], qe_l[i*132 + 2*pr+1]);
  }
  #pragma unroll
  for (int rep = 0; rep < 2; ++rep) {
    int idx = rep*256 + t, i = idx >> 7, dd = idx & 127;
    ha_lds[i*132 + dd] = (p1[0][i][dd] + p1[1][i][dd]) / (dpart[0][i] + dpart[1][i]);
  }
  __syncthreads();

  // --- E: gcn matvec (transposed, coalesced, 4 rows) ---
  {
    const float* gwT = ws + OFF_GWT;
    float g[4]={0,0,0,0};
    #pragma unroll 2
    for (int kk = 0; kk < 64; ++kk) {
      int k = kh*64 + kk;
      float gw = gwT[k*128+d];
      #pragma unroll
      for (int i = 0; i < 4; ++i) g[i] += gw * ha_lds[i*132 + k];
    }
    #pragma unroll
    for (int i = 0; i < 4; ++i) p2[kh][i][d] = g[i];
  }
  __syncthreads();
  #pragma unroll
  for (int rep = 0; rep < 2; ++rep) {
    int idx = rep*256 + t, i = idx >> 7, dd = idx & 127;
    ws[OFF_HG + (size_t)(r0+i)*128 + dd] = p2[0][i][dd] + p2[1][i][dd] + gcn_b[dd];
  }
}

// ---------------------------------------------------------------------------
// Kernel C (attn+epi fused) = R6 form (qk hoist reverted: R7 proved it null).
// ---------------------------------------------------------------------------
__global__ __launch_bounds__(256, 5) void attn_kernel(
    const float* __restrict__ edge, const float* __restrict__ adj,
    const float* __restrict__ srcm, const float* __restrict__ h,
    const float* __restrict__ out_b, const float* __restrict__ ln_g,
    const float* __restrict__ ln_b, const float* __restrict__ ws,
    float* __restrict__ out)
{
  __shared__ unsigned int e_lds[256*18];  // f16-packed edge rows: 16 data + mask + hole
  __shared__ float s_buf[4*264];          // P2/P3: unnormalized exp. P4+: o_l/px/stat
  __shared__ float part4[4*132];          // ebar partials (half-wave pre-reduced)
  __shared__ float part5[4*132];          // ov partials (half-wave pre-reduced)
  __shared__ float wpart[16];

  // overlay of s_buf after P3 (scores dead once P3's barrier passes)
  float* const s_lds = s_buf;             // [4*264]
  float* const eb_l  = s_buf;             // [132] normalized ebar
  float* const o_l   = s_buf + 132;       // [132] o = ov + WveT@ebar + vb
  float* const px    = s_buf + 264;       // [2][128] out_w matvec partials
  float* const stat  = s_buf + 520;       // [4] LN cross-wave partials

  const int t  = threadIdx.x;
  const int bn = blockIdx.x;
  const int b  = bn >> 8;
  const int hh = t & 3;
  const int mq = t >> 2;
  const unsigned int* wsu = (const unsigned int*)ws;

  const float4* et = (const float4*)(edge + (size_t)bn*8192);

  // ---- prologue: issue chunk-0 edge loads, mask, q/qe regs (all overlap) ----
  float4 va = et[t];          // rows [0,32)
  float4 vb = et[256 + t];    // rows [32,64)
  float mp_my = adj[(size_t)bn*256 + t] * srcm[(size_t)bn*256 + t];

  unsigned int qs_pk[16], qe_pk[16];
  {
    const uint4* qp = (const uint4*)(wsu + OFF_QSP + (size_t)bn*64 + hh*16);
    const uint4* qe = (const uint4*)(wsu + OFF_QEP + (size_t)bn*64 + hh*16);
    #pragma unroll
    for (int j = 0; j < 4; ++j) {
      uint4 a = qp[j];
      qs_pk[4*j+0]=a.x; qs_pk[4*j+1]=a.y; qs_pk[4*j+2]=a.z; qs_pk[4*j+3]=a.w;
      uint4 c = qe[j];
      qe_pk[4*j+0]=c.x; qe_pk[4*j+1]=c.y; qe_pk[4*j+2]=c.z; qe_pk[4*j+3]=c.w;
    }
  }
  float sconst = ws[OFF_SC + (size_t)bn*4 + hh];
  const unsigned int* K0 = wsu + OFF_K0P + (size_t)b*256*64;

  // ---- P1+P2 pipelined: write chunk c, issue chunk c+1, barrier, score c ----
  float exacc = 0.f;
  #pragma unroll
  for (int c = 0; c < 4; ++c) {
    {
      int fi = c*512 + t;
      int row = fi >> 3, c4 = fi & 7;
      uint2 pk;
      pk.x = pkf16(va.x, va.y);
      pk.y = pkf16(va.z, va.w);
      *(uint2*)(e_lds + row*18 + c4*2) = pk;
      int fj = fi + 256;
      int row2 = fj >> 3, c42 = fj & 7;
      uint2 pk2;
      pk2.x = pkf16(vb.x, vb.y);
      pk2.y = pkf16(vb.z, vb.w);
      *(uint2*)(e_lds + row2*18 + c42*2) = pk2;
    }
    if (c == 0) e_lds[t*18 + 16] = __float_as_uint(mp_my);  // all masks, once
    if (c < 3) {                       // issue next chunk while this one computes
      va = et[(c+1)*512 + t];
      vb = et[(c+1)*512 + 256 + t];
    }
    __syncthreads();                   // chunk c visible (disjoint rows per chunk)

    int mm = (c << 6) | mq;
    float acc = sconst;
    __builtin_amdgcn_s_setprio(1);
    const uint4* kr4 = (const uint4*)(K0 + (size_t)mm*64 + hh*16);
    #pragma unroll
    for (int j4 = 0; j4 < 4; ++j4) {
      uint4 kw = kr4[j4];
      acc = fdot2(qs_pk[4*j4+0], kw.x, acc);
      acc = fdot2(qs_pk[4*j4+1], kw.y, acc);
      acc = fdot2(qs_pk[4*j4+2], kw.z, acc);
      acc = fdot2(qs_pk[4*j4+3], kw.w, acc);
    }
    const uint2* er = (const uint2*)(e_lds + mm*18);
    #pragma unroll
    for (int j2 = 0; j2 < 8; ++j2) {
      uint2 w = er[j2];
      acc = fdot2(qe_pk[2*j2+0], w.x, acc);
      acc = fdot2(qe_pk[2*j2+1], w.y, acc);
    }
    __builtin_amdgcn_s_setprio(0);
    float mp = __uint_as_float(e_lds[mm*18 + 16]);
    float ex = (mp == 0.0f) ? 0.0f : __expf(acc);   // no max-sub: |s| << 88
    s_lds[hh*264 + mm] = ex;
    exacc += ex;
  }
  // reduce exp-sums across lanes with same head
  exacc += __shfl_down(exacc, 4);
  exacc += __shfl_down(exacc, 8);
  exacc += __shfl_down(exacc, 16);
  exacc += __shfl_down(exacc, 32);
  if ((t & 63) < 4) wpart[(t >> 6)*4 + hh] = exacc;
  __syncthreads();

  // ---- P3: ebar / ov partials in one m-sweep (unnormalized) ----
  {
    int w   = t >> 6;
    int ms  = t >> 5;
    int hh4 = (t >> 3) & 3, e4 = t & 7;
    int c   = t & 31,  hh5 = c >> 3;
    float p4x=0,p4y=0,p4z=0,p4w=0;
    float p5x=0,p5y=0,p5z=0,p5w=0;
    const unsigned int* vrow = wsu + OFF_V0P + (size_t)b*256*64;
    __builtin_amdgcn_s_setprio(1);
    for (int jm = 0; jm < 32; ++jm) {
      int mm = ms*32 + jm;
      float a4 = s_lds[hh4*264 + mm];
      uint2 wv2 = *(const uint2*)(e_lds + mm*18 + e4*2);
      half2_t e0 = u2h(wv2.x), e1 = u2h(wv2.y);
      p4x += a4*(float)e0.x; p4y += a4*(float)e0.y;
      p4z += a4*(float)e1.x; p4w += a4*(float)e1.y;
      float a5 = s_lds[hh5*264 + mm];
      uint2 vv = *(const uint2*)(vrow + (size_t)mm*64 + c*2);
      half2_t v0 = u2h(vv.x), v1 = u2h(vv.y);
      p5x += a5*(float)v0.x; p5y += a5*(float)v0.y;
      p5z += a5*(float)v1.x; p5w += a5*(float)v1.y;
    }
    __builtin_amdgcn_s_setprio(0);
    // combine slice 2w (lanes 0-31) with slice 2w+1 (lanes 32-63):
    // identical (hh4,e4)/(c) position in opposite half-waves.
    p4x += __shfl_xor(p4x, 32); p4y += __shfl_xor(p4y, 32);
    p4z += __shfl_xor(p4z, 32); p4w += __shfl_xor(p4w, 32);
    p5x += __shfl_xor(p5x, 32); p5y += __shfl_xor(p5y, 32);
    p5z += __shfl_xor(p5z, 32); p5w += __shfl_xor(p5w, 32);
    if ((t & 32) == 0) {
      float4 f4; f4.x=p4x; f4.y=p4y; f4.z=p4z; f4.w=p4w;
      *(float4*)(part4 + w*132 + hh4*32 + e4*4) = f4;
      float4 f5; f5.x=p5x; f5.y=p5y; f5.z=p5z; f5.w=p5w;
      *(float4*)(part5 + w*132 + c*4) = f5;
    }
  }
  __syncthreads();   // s_lds dead after this point; s_buf reused below

  // ---- P4: reduce partials + normalize; ebar -> LDS, ov -> reg ----
  float ov_reg = 0.f;
  if (t < 128) {
    int ht = t >> 5;
    float inv = 1.0f / (wpart[ht] + wpart[4+ht] + wpart[8+ht] + wpart[12+ht]);
    float se = 0.f, s2 = 0.f;
    #pragma unroll
    for (int g = 0; g < 4; ++g) { se += part4[g*132 + t]; s2 += part5[g*132 + t]; }
    eb_l[t] = se * inv;
    ov_reg  = s2 * inv;
  }
  __syncthreads();

  // ---- P5: o = ov + vb + WveT@ebar (t<128; 32-e loop) ----
  if (t < 128) {
    int hd = t >> 5;
    float acc = ov_reg + ws[OFF_VB + t];
    const float* wveT = ws + OFF_WVET;
    #pragma unroll 4
    for (int e = 0; e < 32; ++e) acc += wveT[e*128 + t] * eb_l[hd*32 + e];
    o_l[t] = acc;
  }
  __syncthreads();

  // ---- P6: out_w matvec, split-k over 2 halves (all 256 threads) ----
  {
    int d = t & 127, kh = t >> 7;
    const float* owT = ws + OFF_OWT;
    float xa = 0.f;
    #pragma unroll 4
    for (int kk = 0; kk < 64; ++kk) {
      int k = kh*64 + kk;
      xa += owT[k*128 + d] * o_l[k];
    }
    px[kh*128 + d] = xa;
  }
  __syncthreads();

  // ---- P7: residual + LN stats (t<128 holds x in reg) ----
  float x = 0.f;
  if (t < 128) {
    x = px[t] + px[128 + t] + out_b[t] + h[(size_t)bn*128 + t];
    float s = x, ss = x*x;
    #pragma unroll
    for (int off = 32; off > 0; off >>= 1) {
      s  += __shfl_down(s,  off);
      ss += __shfl_down(ss, off);
    }
    if ((t & 63) == 0) { stat[t >> 6] = s; stat[2 + (t >> 6)] = ss; }
  }
  __syncthreads();

  // ---- P8: LN + HG -> out ----
  if (t < 128) {
    float mu   = (stat[0] + stat[1]) * (1.0f/128.0f);
    float var  = (stat[2] + stat[3]) * (1.0f/128.0f) - mu*mu;
    float rstd = rsqrtf(var + 1e-5f);
    out[(size_t)bn*128 + t] =
        ln_g[t]*(x - mu)*rstd + ln_b[t] + ws[OFF_HG + (size_t)bn*128 + t];
  }
}

// ---------------------------------------------------------------------------
extern "C" void kernel_launch(void* const* d_in, const int* in_sizes, int n_in,
                              void* d_out, int out_size, void* d_ws, size_t ws_size,
                              hipStream_t stream) {
  (void)in_sizes; (void)n_in; (void)out_size; (void)ws_size;
  const float* h     = (const float*)d_in[0];
  const float* adj   = (const float*)d_in[1];
  const float* edge  = (const float*)d_in[2];
  const float* srcm  = (const float*)d_in[3];
  const float* gcn_w = (const float*)d_in[4];
  const float* gcn_b = (const float*)d_in[5];
  const float* edge_w= (const float*)d_in[6];
  const float* edge_b= (const float*)d_in[7];
  const float* wq    = (const float*)d_in[8];
  const float* wk    = (const float*)d_in[9];
  const float* wv    = (const float*)d_in[10];
  const float* bq    = (const float*)d_in[11];
  const float* bk    = (const float*)d_in[12];
  const float* bv    = (const float*)d_in[13];
  const float* out_w = (const float*)d_in[14];
  const float* out_b = (const float*)d_in[15];
  const float* ln_g  = (const float*)d_in[16];
  const float* ln_b  = (const float*)d_in[17];

  float* ws  = (float*)d_ws;   // needs >= 3.6 MB
  float* out = (float*)d_out;

  prep_kernel<<<353, 256, 0, stream>>>(wq, wk, wv, out_w, gcn_w, edge_w, edge_b, bk, bv, ws);
  proj_kernel<<<512, 256, 0, stream>>>(h, adj, bq, gcn_b, ws);
  attn_kernel<<<2048, 256, 0, stream>>>(edge, adj, srcm, h, out_b, ln_g, ln_b, ws, out);
}

// Round 9
// 184.707 us; speedup vs baseline: 1.0899x; 1.0899x over previous
//
#include <hip/hip_runtime.h>
#include <hip/hip_bf16.h>

// B=8, N=256, D=128, E=32, H=4, HD=32
// ws layout (float/u32 offsets)
#define OFF_WQT 0          // 16384 transposed wq  [k][d]
#define OFF_WKT 16384
#define OFF_WVT 32768
#define OFF_OWT 49152      // transposed out_w [k][d]
#define OFF_GWT 65536      // transposed gcn_w [k][d]
#define OFF_WKE 81920      // 4096: wk@edge_w, row-major [d][e]
#define OFF_WVET 86016     // 4096: (wv@edge_w)^T, [e][d]
#define OFF_KB  90112      // 128 f32
#define OFF_VB  90240      // 128 f32
#define OFF_SC  90368      // 8192: per-row per-head score const
#define OFF_QSP 98560      // 131072 u32: q/sqrt(HD) packed f16 pairs (64/row)
#define OFF_QEP 229632     // 131072 u32: qe packed f16 pairs
#define OFF_HG  360704     // 262144 f32: gcn branch output (incl gcn_b)
#define OFF_K0P 622848     // 131072 u32: K0 packed f16 (64/row)
#define OFF_V0P 753920     // 131072 u32: V0 packed f16
// total 885 Kf = 3.54 MB

// gfx950 builtins use the __fp16 ext-vector type (NOT _Float16)
using half2_t = __attribute__((ext_vector_type(2))) __fp16;

static __device__ __forceinline__ half2_t u2h(unsigned int u){
  union { unsigned int u; half2_t h; } x; x.u = u; return x.h;
}
static __device__ __forceinline__ unsigned int pkf16(float a, float b){
  union { half2_t h; unsigned int u; } x;
  x.h = __builtin_amdgcn_cvt_pkrtz(a, b);
  return x.u;
}
static __device__ __forceinline__ float fdot2(unsigned int a, unsigned int b, float c){
  return __builtin_amdgcn_fdot2(u2h(a), u2h(b), c, false);
}

// ---------------------------------------------------------------------------
// Kernel A (prep): 5 weight transposes + Wke / WveT + fused biases.
// ---------------------------------------------------------------------------
__global__ __launch_bounds__(256) void prep_kernel(
    const float* __restrict__ wq, const float* __restrict__ wk,
    const float* __restrict__ wv, const float* __restrict__ out_w,
    const float* __restrict__ gcn_w, const float* __restrict__ edge_w,
    const float* __restrict__ edge_b, const float* __restrict__ bk,
    const float* __restrict__ bv, float* __restrict__ ws)
{
  int blk = blockIdx.x, t = threadIdx.x;
  if (blk < 320) {
    int w = blk >> 6;
    int e0 = (blk & 63) * 256 + t;
    const float* src = (w==0) ? wq : (w==1) ? wk : (w==2) ? wv : (w==3) ? out_w : gcn_w;
    float* dst = ws + ((w==0) ? OFF_WQT : (w==1) ? OFF_WKT : (w==2) ? OFF_WVT
                      : (w==3) ? OFF_OWT : OFF_GWT);
    int k = e0 >> 7, d = e0 & 127;
    dst[e0] = src[d*128 + k];
  } else if (blk < 352) {
    int idx = blk - 320;
    int which = idx >> 4;                  // 0: Wke (row-major), 1: WveT (transposed)
    int e0 = (idx & 15) * 256 + t;
    int dd = e0 >> 5, e = e0 & 31;
    const float* W = which ? wv : wk;
    float acc = 0.f;
    #pragma unroll 4
    for (int k2 = 0; k2 < 128; ++k2) acc += W[dd*128+k2] * edge_w[k2*32+e];
    if (which) ws[OFF_WVET + e*128 + dd] = acc;
    else       ws[OFF_WKE + e0] = acc;
  } else {
    int dd = t & 127;
    const float* W  = (t < 128) ? wk : wv;
    const float* bb = (t < 128) ? bk : bv;
    float acc = bb[dd];
    #pragma unroll 4
    for (int k2 = 0; k2 < 128; ++k2) acc += W[dd*128+k2] * edge_b[k2];
    ws[((t < 128) ? OFF_KB : OFF_VB) + dd] = acc;
  }
}

// ---------------------------------------------------------------------------
// Kernel B (proj) = v1 (2 rows/block, grid 1024). R8's 4-row variant
// regressed (+15us: 25KB LDS + doubled serial work); reverted.
// ---------------------------------------------------------------------------
__global__ __launch_bounds__(256) void proj_kernel(
    const float* __restrict__ h, const float* __restrict__ adj,
    const float* __restrict__ bq, const float* __restrict__ gcn_b,
    float* __restrict__ ws)
{
  __shared__ float h_lds[256];        // 2 x 128
  __shared__ float adj_lds[512];      // 2 x 256
  __shared__ float p1[2][2][128];
  __shared__ float p2[2][2][128];
  __shared__ float p3[2][2][128];
  __shared__ float qrow[2*132];
  __shared__ float qe_l[2*132];
  __shared__ float dpart[2][2];
  __shared__ float ha_lds[2*132];

  int t = threadIdx.x;
  int d = t & 127, kh = t >> 7;
  int r0 = blockIdx.x * 2;
  int b  = r0 >> 8, n0 = r0 & 255;
  unsigned int* wsu = (unsigned int*)ws;

  if (t < 64)  ((float4*)h_lds)[t]   = ((const float4*)(h   + (size_t)r0*128))[t];
  if (t < 128) ((float4*)adj_lds)[t] = ((const float4*)(adj + (size_t)r0*256))[t];
  __syncthreads();

  // --- A: qkv matvecs, transposed weights (lane-d coalesced) ---
  {
    const float* wqT = ws + OFF_WQT;
    const float* wkT = ws + OFF_WKT;
    const float* wvT = ws + OFF_WVT;
    float aq0=0,aq1=0,ak0=0,ak1=0,av0=0,av1=0;
    #pragma unroll 4
    for (int kk = 0; kk < 64; ++kk) {
      int k = kh*64 + kk;
      float qw = wqT[k*128+d], kw = wkT[k*128+d], vw = wvT[k*128+d];
      float h0 = h_lds[k], h1 = h_lds[128+k];
      aq0 += qw*h0; aq1 += qw*h1;
      ak0 += kw*h0; ak1 += kw*h1;
      av0 += vw*h0; av1 += vw*h1;
    }
    p1[kh][0][d]=aq0; p1[kh][1][d]=aq1;
    p2[kh][0][d]=ak0; p2[kh][1][d]=ak1;
    p3[kh][0][d]=av0; p3[kh][1][d]=av1;
  }
  __syncthreads();

  // --- B: qrow (f32 LDS) + K/V pack to global ---
  {
    int i = t >> 7, dd = t & 127;
    const float inv = 0.17677669529663687f;   // 1/sqrt(32)
    qrow[i*132 + dd] = (p1[0][i][dd] + p1[1][i][dd] + bq[dd]) * inv;
  }
  {
    int i = (t >> 6) & 1, pr = t & 63;
    if (t < 128) {
      float k0 = p2[0][i][2*pr] + p2[1][i][2*pr];
      float k1 = p2[0][i][2*pr+1] + p2[1][i][2*pr+1];
      wsu[OFF_K0P + (size_t)(r0+i)*64 + pr] = pkf16(k0, k1);
    } else {
      float v0 = p3[0][i][2*pr] + p3[1][i][2*pr];
      float v1 = p3[0][i][2*pr+1] + p3[1][i][2*pr+1];
      wsu[OFF_V0P + (size_t)(r0+i)*64 + pr] = pkf16(v0, v1);
    }
  }
  __syncthreads();   // qrow ready; p1..p3 free

  // --- C: qs-pack, qe compute, sc, GCN aggregation ---
  if (t < 128) {
    int i = t >> 6, pr = t & 63;
    wsu[OFF_QSP + (size_t)(r0+i)*64 + pr] = pkf16(qrow[i*132 + 2*pr], qrow[i*132 + 2*pr+1]);
  }
  {
    int i = t >> 7, he = t & 127, hh = he >> 5, e = he & 31;
    float acc = 0.f;
    #pragma unroll
    for (int j = 0; j < 32; ++j)
      acc += ws[OFF_WKE + (hh*32 + j)*32 + e] * qrow[i*132 + hh*32 + j];
    qe_l[i*132 + he] = acc;
  }
  if (t < 8) {
    int i = t >> 2, hh = t & 3;
    float acc = 0.f;
    #pragma unroll
    for (int j = 0; j < 32; ++j)
      acc += qrow[i*132 + hh*32 + j] * ws[OFF_KB + hh*32 + j];
    ws[OFF_SC + (size_t)(r0+i)*4 + hh] = acc;
  }
  {
    float ag0=0, ag1=0, dg0=0, dg1=0;
    #pragma unroll 4
    for (int mm = 0; mm < 128; ++mm) {
      int ml = kh*128 + mm;
      float hv = h[((size_t)b*256 + ml)*128 + d];
      float a0 = adj_lds[ml]       + ((ml == n0)     ? 1.0f : 0.0f);
      float a1 = adj_lds[256 + ml] + ((ml == n0 + 1) ? 1.0f : 0.0f);
      ag0 += a0*hv; ag1 += a1*hv; dg0 += a0; dg1 += a1;
    }
    p1[kh][0][d]=ag0; p1[kh][1][d]=ag1;
    if (d == 0) { dpart[kh][0]=dg0; dpart[kh][1]=dg1; }
  }
  __syncthreads();

  // --- D: qe-pack + ha ---
  if (t < 128) {
    int i = t >> 6, pr = t & 63;
    wsu[OFF_QEP + (size_t)(r0+i)*64 + pr] = pkf16(qe_l[i*132 + 2*pr], qe_l[i*132 + 2*pr+1]);
  }
  {
    int i = t >> 7, dd = t & 127;
    ha_lds[i*132 + dd] = (p1[0][i][dd] + p1[1][i][dd]) / (dpart[0][i] + dpart[1][i]);
  }
  __syncthreads();

  // --- E: gcn matvec (transposed, coalesced) ---
  {
    const float* gwT = ws + OFF_GWT;
    float g0=0, g1=0;
    #pragma unroll 4
    for (int kk = 0; kk < 64; ++kk) {
      int k = kh*64 + kk;
      float gw = gwT[k*128+d];
      g0 += gw * ha_lds[k];
      g1 += gw * ha_lds[132 + k];
    }
    p2[kh][0][d]=g0; p2[kh][1][d]=g1;
  }
  __syncthreads();
  {
    int i = t >> 7, dd = t & 127;
    ws[OFF_HG + (size_t)(r0+i)*128 + dd] = p2[0][i][dd] + p2[1][i][dd] + gcn_b[dd];
  }
}

// ---------------------------------------------------------------------------
// Kernel C (attn+epi fused), R9: R4's chunk-fused register-accumulator
// structure with the spill defect removed:
//  - qs/qe packed operands live in LDS (512 B, ds_read_b128), NOT 32 VGPRs.
//  - NO occupancy pin (plain launch_bounds(256)): allocator free -> no spill.
//  - LDS ~13.9 KB -> 8 blocks/CU (wave-capped); whole grid resident.
// Per chunk: stage+prefetch | BAR | score | BAR | p4/p5 reg-accum (wave-split).
// ---------------------------------------------------------------------------
__global__ __launch_bounds__(256) void attn_kernel(
    const float* __restrict__ edge, const float* __restrict__ adj,
    const float* __restrict__ srcm, const float* __restrict__ h,
    const float* __restrict__ out_b, const float* __restrict__ ln_g,
    const float* __restrict__ ln_b, const float* __restrict__ ws,
    float* __restrict__ out)
{
  __shared__ unsigned int e_buf[2*64*18];  // 2 chunk bufs, 64 rows x (16 data + 2 pad)
  __shared__ unsigned int q_lds[128];      // qs (64) + qe (64) packed words
  __shared__ float s_chunk[4*66];          // unnormalized exp, this chunk
  __shared__ float wpart[16];
  __shared__ float ovh[128];               // wave-3 ov partials (64 float2)
  __shared__ float eb_l[128];
  __shared__ float ov_l[128];
  __shared__ float o_l[128];
  __shared__ float px[256];
  __shared__ float stat[4];

  const int t  = threadIdx.x;
  const int bn = blockIdx.x;
  const int b  = bn >> 8;
  const int hh = t & 3;
  const int mq = t >> 2;                   // chunk-local row for score phase
  const unsigned int* wsu = (const unsigned int*)ws;

  const float4* et = (const float4*)(edge + (size_t)bn*8192);

  // ---- prologue: chunk-0 edge loads, masks, q/qe -> LDS, tail prefetch ----
  float4 va = et[t];          // chunk rows [0,32)
  float4 vb = et[256 + t];    // chunk rows [32,64)
  float mp0 = adj[(size_t)bn*256 +       mq] * srcm[(size_t)bn*256 +       mq];
  float mp1 = adj[(size_t)bn*256 +  64 + mq] * srcm[(size_t)bn*256 +  64 + mq];
  float mp2 = adj[(size_t)bn*256 + 128 + mq] * srcm[(size_t)bn*256 + 128 + mq];
  float mp3 = adj[(size_t)bn*256 + 192 + mq] * srcm[(size_t)bn*256 + 192 + mq];

  if (t < 64)       q_lds[t]      = wsu[OFF_QSP + (size_t)bn*64 + t];
  else if (t < 128) q_lds[t]      = wsu[OFF_QEP + (size_t)bn*64 + (t - 64)];

  float sconst = ws[OFF_SC + (size_t)bn*4 + hh];
  const unsigned int* K0 = wsu + OFF_K0P + (size_t)b*256*64;

  float h_pre = 0.f, hg_pre = 0.f;
  if (t < 128) {
    h_pre  = h[(size_t)bn*128 + t];
    hg_pre = ws[OFF_HG + (size_t)bn*128 + t];
  }

  // persistent accumulators (role-split by wave)
  float exacc = 0.f;
  float acc4 = 0.f;                 // t<128: ebar(ht=t>>5, e=t&31)
  float acc5x = 0.f, acc5y = 0.f;   // t>=128: ov d-pair (j=(t-128)&63, mh=(t-128)>>6)

  // ---- main loop: 4 chunks of 64 m-rows ----
  #pragma unroll
  for (int c = 0; c < 4; ++c) {
    unsigned int* eb = e_buf + (c & 1)*64*18;
    {
      int lr = t >> 3, c4 = t & 7;
      uint2 pk;
      pk.x = pkf16(va.x, va.y); pk.y = pkf16(va.z, va.w);
      *(uint2*)(eb + lr*18 + c4*2) = pk;
      uint2 pk2;
      pk2.x = pkf16(vb.x, vb.y); pk2.y = pkf16(vb.z, vb.w);
      *(uint2*)(eb + (32 + lr)*18 + c4*2) = pk2;
    }
    if (c < 3) {                    // prefetch next chunk while this computes
      va = et[(c+1)*512 + t];
      vb = et[(c+1)*512 + 256 + t];
    }
    __syncthreads();                // chunk c staged; q_lds ready (c=0);
                                    // also orders p3(c-1) before score(c)

    // score: thread (hh, mq) -> ex for chunk row mq
    {
      int gm = c*64 + mq;
      float acc = sconst;
      const uint4* kr4 = (const uint4*)(K0 + (size_t)gm*64 + hh*16);
      const uint4* qs4 = (const uint4*)(q_lds + hh*16);
      const uint4* qe4 = (const uint4*)(q_lds + 64 + hh*16);
      #pragma unroll
      for (int j4 = 0; j4 < 4; ++j4) {
        uint4 kw = kr4[j4];
        uint4 qw = qs4[j4];
        acc = fdot2(qw.x, kw.x, acc);
        acc = fdot2(qw.y, kw.y, acc);
        acc = fdot2(qw.z, kw.z, acc);
        acc = fdot2(qw.w, kw.w, acc);
      }
      const uint2* er = (const uint2*)(eb + mq*18);
      #pragma unroll
      for (int j4 = 0; j4 < 4; ++j4) {
        uint4 qw = qe4[j4];
        uint2 w0 = er[2*j4], w1 = er[2*j4+1];
        acc = fdot2(qw.x, w0.x, acc);
        acc = fdot2(qw.y, w0.y, acc);
        acc = fdot2(qw.z, w1.x, acc);
        acc = fdot2(qw.w, w1.y, acc);
      }
      float mp = (c==0) ? mp0 : (c==1) ? mp1 : (c==2) ? mp2 : mp3;
      float ex = (mp == 0.0f) ? 0.0f : __expf(acc);   // no max-sub: |s| << 88
      s_chunk[hh*66 + mq] = ex;
      exacc += ex;
    }
    __syncthreads();                // s_chunk ready

    // p3: register accumulation, wave-split
    if (t < 128) {
      // ebar(ht, e) += sum_m ex[ht][m] * edge_f16[m][e]
      int e = t & 31, ht = t >> 5;
      const float* sc_ = s_chunk + ht*66;
      const unsigned int* ebr = eb + (e >> 1);
      bool hi = (e & 1);
      float a0 = 0.f, a1 = 0.f;
      #pragma unroll 8
      for (int m = 0; m < 64; m += 2) {
        float s0 = sc_[m], s1 = sc_[m+1];
        half2_t w0 = u2h(ebr[m*18]);
        half2_t w1 = u2h(ebr[(m+1)*18]);
        float e0 = hi ? (float)w0.y : (float)w0.x;
        float e1 = hi ? (float)w1.y : (float)w1.x;
        a0 += s0*e0; a1 += s1*e1;
      }
      acc4 += a0 + a1;
    } else {
      // ov d-pair (d=2j,2j+1) += sum_m ex[head][m] * V0[m][d]; m-halved by wave
      int idx = t - 128;
      int j = idx & 63, mh = idx >> 6;
      int head = j >> 4;
      const float* sc_ = s_chunk + head*66 + mh*32;
      const unsigned int* vp = wsu + OFF_V0P + ((size_t)b*256 + c*64 + mh*32)*64 + j;
      float a0 = 0.f, a1 = 0.f;
      #pragma unroll 8
      for (int m = 0; m < 32; ++m) {
        float s = sc_[m];
        half2_t v = u2h(vp[(size_t)m*64]);
        a0 += s*(float)v.x; a1 += s*(float)v.y;
      }
      acc5x += a0; acc5y += a1;
    }
  }

  // ---- exp-sum reduce (same-head lanes within wave) ----
  exacc += __shfl_down(exacc, 4);
  exacc += __shfl_down(exacc, 8);
  exacc += __shfl_down(exacc, 16);
  exacc += __shfl_down(exacc, 32);
  if ((t & 63) < 4) wpart[(t >> 6)*4 + hh] = exacc;
  if (t >= 192) {                       // wave-3 ov partials -> LDS
    int j = (t - 128) & 63;
    float2 p; p.x = acc5x; p.y = acc5y;
    *(float2*)(ovh + j*2) = p;
  }
  __syncthreads();

  // ---- P4: normalize; ebar -> eb_l, ov (+vb) -> ov_l ----
  if (t < 128) {
    int ht = t >> 5;
    float inv = 1.0f / (wpart[ht] + wpart[4+ht] + wpart[8+ht] + wpart[12+ht]);
    eb_l[t] = acc4 * inv;
  } else if (t < 192) {
    int j = t - 128, head = j >> 4;
    float inv = 1.0f / (wpart[head] + wpart[4+head] + wpart[8+head] + wpart[12+head]);
    float2 oh = *(const float2*)(ovh + j*2);
    float2 res;
    res.x = (acc5x + oh.x)*inv + ws[OFF_VB + 2*j];
    res.y = (acc5y + oh.y)*inv + ws[OFF_VB + 2*j + 1];
    *(float2*)(ov_l + 2*j) = res;
  }
  __syncthreads();

  // ---- P5: o = ov + vb + WveT@ebar (t<128) ----
  if (t < 128) {
    int hd = t >> 5;
    float acc = ov_l[t];
    const float* wveT = ws + OFF_WVET;
    #pragma unroll 8
    for (int e = 0; e < 32; ++e) acc += wveT[e*128 + t] * eb_l[hd*32 + e];
    o_l[t] = acc;
  }
  __syncthreads();

  // ---- P6: out_w matvec, split-k over 2 halves (all 256 threads) ----
  {
    int d = t & 127, kh = t >> 7;
    const float* owT = ws + OFF_OWT;
    float xa = 0.f;
    #pragma unroll 8
    for (int kk = 0; kk < 64; ++kk) {
      int k = kh*64 + kk;
      xa += owT[k*128 + d] * o_l[k];
    }
    px[kh*128 + d] = xa;
  }
  __syncthreads();

  // ---- P7: residual + LN stats (t<128 holds x in reg) ----
  float x = 0.f;
  if (t < 128) {
    x = px[t] + px[128 + t] + out_b[t] + h_pre;
    float s = x, ss = x*x;
    #pragma unroll
    for (int off = 32; off > 0; off >>= 1) {
      s  += __shfl_down(s,  off);
      ss += __shfl_down(ss, off);
    }
    if ((t & 63) == 0) { stat[t >> 6] = s; stat[2 + (t >> 6)] = ss; }
  }
  __syncthreads();

  // ---- P8: LN + HG -> out ----
  if (t < 128) {
    float mu   = (stat[0] + stat[1]) * (1.0f/128.0f);
    float var  = (stat[2] + stat[3]) * (1.0f/128.0f) - mu*mu;
    float rstd = rsqrtf(var + 1e-5f);
    out[(size_t)bn*128 + t] =
        ln_g[t]*(x - mu)*rstd + ln_b[t] + hg_pre;
  }
}

// ---------------------------------------------------------------------------
extern "C" void kernel_launch(void* const* d_in, const int* in_sizes, int n_in,
                              void* d_out, int out_size, void* d_ws, size_t ws_size,
                              hipStream_t stream) {
  (void)in_sizes; (void)n_in; (void)out_size; (void)ws_size;
  const float* h     = (const float*)d_in[0];
  const float* adj   = (const float*)d_in[1];
  const float* edge  = (const float*)d_in[2];
  const float* srcm  = (const float*)d_in[3];
  const float* gcn_w = (const float*)d_in[4];
  const float* gcn_b = (const float*)d_in[5];
  const float* edge_w= (const float*)d_in[6];
  const float* edge_b= (const float*)d_in[7];
  const float* wq    = (const float*)d_in[8];
  const float* wk    = (const float*)d_in[9];
  const float* wv    = (const float*)d_in[10];
  const float* bq    = (const float*)d_in[11];
  const float* bk    = (const float*)d_in[12];
  const float* bv    = (const float*)d_in[13];
  const float* out_w = (const float*)d_in[14];
  const float* out_b = (const float*)d_in[15];
  const float* ln_g  = (const float*)d_in[16];
  const float* ln_b  = (const float*)d_in[17];

  float* ws  = (float*)d_ws;   // needs >= 3.6 MB
  float* out = (float*)d_out;

  prep_kernel<<<353, 256, 0, stream>>>(wq, wk, wv, out_w, gcn_w, edge_w, edge_b, bk, bv, ws);
  proj_kernel<<<1024, 256, 0, stream>>>(h, adj, bq, gcn_b, ws);
  attn_kernel<<<2048, 256, 0, stream>>>(edge, adj, srcm, h, out_b, ln_g, ln_b, ws, out);
}

// Round 10
// 183.966 us; speedup vs baseline: 1.0942x; 1.0040x over previous
//
#include <hip/hip_runtime.h>
#include <hip/hip_bf16.h>

// B=8, N=256, D=128, E=32, H=4, HD=32
// ws layout (float/u32 offsets)
#define OFF_WQT 0          // 16384 transposed wq  [k][d]
#define OFF_WKT 16384
#define OFF_WVT 32768
#define OFF_OWT 49152      // transposed out_w [k][d]
#define OFF_GWT 65536      // transposed gcn_w [k][d]
#define OFF_WKE 81920      // 4096: wk@edge_w, row-major [d][e]
#define OFF_WVET 86016     // 4096: (wv@edge_w)^T, [e][d]
#define OFF_KB  90112      // 128 f32
#define OFF_VB  90240      // 128 f32
#define OFF_SC  90368      // 8192: per-row per-head score const
#define OFF_QSP 98560      // 131072 u32: q/sqrt(HD) packed f16 pairs (64/row)
#define OFF_QEP 229632     // 131072 u32: qe packed f16 pairs
#define OFF_HG  360704     // 262144 f32: gcn branch output (incl gcn_b)
#define OFF_K0P 622848     // 131072 u32: K0 packed f16 (64/row)
#define OFF_V0P 753920     // 131072 u32: V0 packed f16
// total 885 Kf = 3.54 MB

// gfx950 builtins use the __fp16 ext-vector type (NOT _Float16)
using half2_t = __attribute__((ext_vector_type(2))) __fp16;

static __device__ __forceinline__ half2_t u2h(unsigned int u){
  union { unsigned int u; half2_t h; } x; x.u = u; return x.h;
}
static __device__ __forceinline__ unsigned int pkf16(float a, float b){
  union { half2_t h; unsigned int u; } x;
  x.h = __builtin_amdgcn_cvt_pkrtz(a, b);
  return x.u;
}
static __device__ __forceinline__ float fdot2(unsigned int a, unsigned int b, float c){
  return __builtin_amdgcn_fdot2(u2h(a), u2h(b), c, false);
}

// ---------------------------------------------------------------------------
// Kernel A (prep): 5 weight transposes + Wke / WveT + fused biases.
// ---------------------------------------------------------------------------
__global__ __launch_bounds__(256) void prep_kernel(
    const float* __restrict__ wq, const float* __restrict__ wk,
    const float* __restrict__ wv, const float* __restrict__ out_w,
    const float* __restrict__ gcn_w, const float* __restrict__ edge_w,
    const float* __restrict__ edge_b, const float* __restrict__ bk,
    const float* __restrict__ bv, float* __restrict__ ws)
{
  int blk = blockIdx.x, t = threadIdx.x;
  if (blk < 320) {
    int w = blk >> 6;
    int e0 = (blk & 63) * 256 + t;
    const float* src = (w==0) ? wq : (w==1) ? wk : (w==2) ? wv : (w==3) ? out_w : gcn_w;
    float* dst = ws + ((w==0) ? OFF_WQT : (w==1) ? OFF_WKT : (w==2) ? OFF_WVT
                      : (w==3) ? OFF_OWT : OFF_GWT);
    int k = e0 >> 7, d = e0 & 127;
    dst[e0] = src[d*128 + k];
  } else if (blk < 352) {
    int idx = blk - 320;
    int which = idx >> 4;                  // 0: Wke (row-major), 1: WveT (transposed)
    int e0 = (idx & 15) * 256 + t;
    int dd = e0 >> 5, e = e0 & 31;
    const float* W = which ? wv : wk;
    float acc = 0.f;
    #pragma unroll 4
    for (int k2 = 0; k2 < 128; ++k2) acc += W[dd*128+k2] * edge_w[k2*32+e];
    if (which) ws[OFF_WVET + e*128 + dd] = acc;
    else       ws[OFF_WKE + e0] = acc;
  } else {
    int dd = t & 127;
    const float* W  = (t < 128) ? wk : wv;
    const float* bb = (t < 128) ? bk : bv;
    float acc = bb[dd];
    #pragma unroll 4
    for (int k2 = 0; k2 < 128; ++k2) acc += W[dd*128+k2] * edge_b[k2];
    ws[((t < 128) ? OFF_KB : OFF_VB) + dd] = acc;
  }
}

// ---------------------------------------------------------------------------
// Kernel B (proj) = v1 (2 rows/block, grid 1024).
// ---------------------------------------------------------------------------
__global__ __launch_bounds__(256) void proj_kernel(
    const float* __restrict__ h, const float* __restrict__ adj,
    const float* __restrict__ bq, const float* __restrict__ gcn_b,
    float* __restrict__ ws)
{
  __shared__ float h_lds[256];        // 2 x 128
  __shared__ float adj_lds[512];      // 2 x 256
  __shared__ float p1[2][2][128];
  __shared__ float p2[2][2][128];
  __shared__ float p3[2][2][128];
  __shared__ float qrow[2*132];
  __shared__ float qe_l[2*132];
  __shared__ float dpart[2][2];
  __shared__ float ha_lds[2*132];

  int t = threadIdx.x;
  int d = t & 127, kh = t >> 7;
  int r0 = blockIdx.x * 2;
  int b  = r0 >> 8, n0 = r0 & 255;
  unsigned int* wsu = (unsigned int*)ws;

  if (t < 64)  ((float4*)h_lds)[t]   = ((const float4*)(h   + (size_t)r0*128))[t];
  if (t < 128) ((float4*)adj_lds)[t] = ((const float4*)(adj + (size_t)r0*256))[t];
  __syncthreads();

  // --- A: qkv matvecs, transposed weights (lane-d coalesced) ---
  {
    const float* wqT = ws + OFF_WQT;
    const float* wkT = ws + OFF_WKT;
    const float* wvT = ws + OFF_WVT;
    float aq0=0,aq1=0,ak0=0,ak1=0,av0=0,av1=0;
    #pragma unroll 4
    for (int kk = 0; kk < 64; ++kk) {
      int k = kh*64 + kk;
      float qw = wqT[k*128+d], kw = wkT[k*128+d], vw = wvT[k*128+d];
      float h0 = h_lds[k], h1 = h_lds[128+k];
      aq0 += qw*h0; aq1 += qw*h1;
      ak0 += kw*h0; ak1 += kw*h1;
      av0 += vw*h0; av1 += vw*h1;
    }
    p1[kh][0][d]=aq0; p1[kh][1][d]=aq1;
    p2[kh][0][d]=ak0; p2[kh][1][d]=ak1;
    p3[kh][0][d]=av0; p3[kh][1][d]=av1;
  }
  __syncthreads();

  // --- B: qrow (f32 LDS) + K/V pack to global ---
  {
    int i = t >> 7, dd = t & 127;
    const float inv = 0.17677669529663687f;   // 1/sqrt(32)
    qrow[i*132 + dd] = (p1[0][i][dd] + p1[1][i][dd] + bq[dd]) * inv;
  }
  {
    int i = (t >> 6) & 1, pr = t & 63;
    if (t < 128) {
      float k0 = p2[0][i][2*pr] + p2[1][i][2*pr];
      float k1 = p2[0][i][2*pr+1] + p2[1][i][2*pr+1];
      wsu[OFF_K0P + (size_t)(r0+i)*64 + pr] = pkf16(k0, k1);
    } else {
      float v0 = p3[0][i][2*pr] + p3[1][i][2*pr];
      float v1 = p3[0][i][2*pr+1] + p3[1][i][2*pr+1];
      wsu[OFF_V0P + (size_t)(r0+i)*64 + pr] = pkf16(v0, v1);
    }
  }
  __syncthreads();   // qrow ready; p1..p3 free

  // --- C: qs-pack, qe compute, sc, GCN aggregation ---
  if (t < 128) {
    int i = t >> 6, pr = t & 63;
    wsu[OFF_QSP + (size_t)(r0+i)*64 + pr] = pkf16(qrow[i*132 + 2*pr], qrow[i*132 + 2*pr+1]);
  }
  {
    int i = t >> 7, he = t & 127, hh = he >> 5, e = he & 31;
    float acc = 0.f;
    #pragma unroll
    for (int j = 0; j < 32; ++j)
      acc += ws[OFF_WKE + (hh*32 + j)*32 + e] * qrow[i*132 + hh*32 + j];
    qe_l[i*132 + he] = acc;
  }
  if (t < 8) {
    int i = t >> 2, hh = t & 3;
    float acc = 0.f;
    #pragma unroll
    for (int j = 0; j < 32; ++j)
      acc += qrow[i*132 + hh*32 + j] * ws[OFF_KB + hh*32 + j];
    ws[OFF_SC + (size_t)(r0+i)*4 + hh] = acc;
  }
  {
    float ag0=0, ag1=0, dg0=0, dg1=0;
    #pragma unroll 4
    for (int mm = 0; mm < 128; ++mm) {
      int ml = kh*128 + mm;
      float hv = h[((size_t)b*256 + ml)*128 + d];
      float a0 = adj_lds[ml]       + ((ml == n0)     ? 1.0f : 0.0f);
      float a1 = adj_lds[256 + ml] + ((ml == n0 + 1) ? 1.0f : 0.0f);
      ag0 += a0*hv; ag1 += a1*hv; dg0 += a0; dg1 += a1;
    }
    p1[kh][0][d]=ag0; p1[kh][1][d]=ag1;
    if (d == 0) { dpart[kh][0]=dg0; dpart[kh][1]=dg1; }
  }
  __syncthreads();

  // --- D: qe-pack + ha ---
  if (t < 128) {
    int i = t >> 6, pr = t & 63;
    wsu[OFF_QEP + (size_t)(r0+i)*64 + pr] = pkf16(qe_l[i*132 + 2*pr], qe_l[i*132 + 2*pr+1]);
  }
  {
    int i = t >> 7, dd = t & 127;
    ha_lds[i*132 + dd] = (p1[0][i][dd] + p1[1][i][dd]) / (dpart[0][i] + dpart[1][i]);
  }
  __syncthreads();

  // --- E: gcn matvec (transposed, coalesced) ---
  {
    const float* gwT = ws + OFF_GWT;
    float g0=0, g1=0;
    #pragma unroll 4
    for (int kk = 0; kk < 64; ++kk) {
      int k = kh*64 + kk;
      float gw = gwT[k*128+d];
      g0 += gw * ha_lds[k];
      g1 += gw * ha_lds[132 + k];
    }
    p2[kh][0][d]=g0; p2[kh][1][d]=g1;
  }
  __syncthreads();
  {
    int i = t >> 7, dd = t & 127;
    ws[OFF_HG + (size_t)(r0+i)*128 + dd] = p2[0][i][dd] + p2[1][i][dd] + gcn_b[dd];
  }
}

// ---------------------------------------------------------------------------
// Kernel C (attn+epi fused), R10: R9 chunk-fused structure with ONE barrier
// per chunk. Triple-buffered e_buf + double-buffered s_chunk make the three
// per-chunk activities conflict-free in a single phase:
//   phase c: score(c) [buf c%3] | p3(c-1) [buf (c-1)%3, s_chunk (c-1)&1]
//            | LDS-write chunk c+1 [buf (c+1)%3] | issue loads chunk c+2
// Score's K0/fdot2 stream interleaves with p3's LDS-FMA stream in one
// instruction stream -> intra-thread latency overlap. 13 -> 10 barriers.
// ---------------------------------------------------------------------------
__global__ __launch_bounds__(256) void attn_kernel(
    const float* __restrict__ edge, const float* __restrict__ adj,
    const float* __restrict__ srcm, const float* __restrict__ h,
    const float* __restrict__ out_b, const float* __restrict__ ln_g,
    const float* __restrict__ ln_b, const float* __restrict__ ws,
    float* __restrict__ out)
{
  __shared__ unsigned int e_buf[3*64*18];  // 3 chunk bufs, 64 rows x (16 data + 2 pad)
  __shared__ unsigned int q_lds[128];      // qs (64) + qe (64) packed words
  __shared__ float s_chunk[2][4*66];       // unnormalized exp, double-buffered
  __shared__ float wpart[16];
  __shared__ float ovh[128];               // wave-3 ov partials (64 float2)
  __shared__ float eb_l[128];
  __shared__ float ov_l[128];
  __shared__ float o_l[128];
  __shared__ float px[256];
  __shared__ float stat[4];

  const int t  = threadIdx.x;
  const int bn = blockIdx.x;
  const int b  = bn >> 8;
  const int hh = t & 3;
  const int mq = t >> 2;                   // chunk-local row for score phase
  const unsigned int* wsu = (const unsigned int*)ws;

  const float4* et = (const float4*)(edge + (size_t)bn*8192);

  // ---- prologue: chunk-0 staged, chunk-1 in flight, masks, q/qe -> LDS ----
  float4 va = et[t];          // chunk 0 rows [0,32)
  float4 vb = et[256 + t];    // chunk 0 rows [32,64)
  float mp0 = adj[(size_t)bn*256 +       mq] * srcm[(size_t)bn*256 +       mq];
  float mp1 = adj[(size_t)bn*256 +  64 + mq] * srcm[(size_t)bn*256 +  64 + mq];
  float mp2 = adj[(size_t)bn*256 + 128 + mq] * srcm[(size_t)bn*256 + 128 + mq];
  float mp3 = adj[(size_t)bn*256 + 192 + mq] * srcm[(size_t)bn*256 + 192 + mq];

  if (t < 64)       q_lds[t] = wsu[OFF_QSP + (size_t)bn*64 + t];
  else if (t < 128) q_lds[t] = wsu[OFF_QEP + (size_t)bn*64 + (t - 64)];

  float sconst = ws[OFF_SC + (size_t)bn*4 + hh];
  const unsigned int* K0 = wsu + OFF_K0P + (size_t)b*256*64;

  float h_pre = 0.f, hg_pre = 0.f;
  if (t < 128) {
    h_pre  = h[(size_t)bn*128 + t];
    hg_pre = ws[OFF_HG + (size_t)bn*128 + t];
  }

  {
    int lr = t >> 3, c4 = t & 7;
    uint2 pk;
    pk.x = pkf16(va.x, va.y); pk.y = pkf16(va.z, va.w);
    *(uint2*)(e_buf + lr*18 + c4*2) = pk;
    uint2 pk2;
    pk2.x = pkf16(vb.x, vb.y); pk2.y = pkf16(vb.z, vb.w);
    *(uint2*)(e_buf + (32 + lr)*18 + c4*2) = pk2;
  }
  va = et[512 + t];           // issue chunk 1
  vb = et[768 + t];
  __syncthreads();            // buf0 + q_lds visible

  // persistent accumulators (role-split by wave)
  float exacc = 0.f;
  float acc4 = 0.f;                 // t<128: ebar(ht=t>>5, e=t&31)
  float acc5x = 0.f, acc5y = 0.f;   // t>=128: ov d-pair

  // ---- main loop: 4 chunks, ONE barrier each ----
  #pragma unroll
  for (int c = 0; c < 4; ++c) {
    const unsigned int* ebc = e_buf + (c % 3)*64*18;       // score source

    // score(c): thread (hh, mq) -> ex for chunk row mq
    {
      int gm = c*64 + mq;
      float acc = sconst;
      const uint4* kr4 = (const uint4*)(K0 + (size_t)gm*64 + hh*16);
      const uint4* qs4 = (const uint4*)(q_lds + hh*16);
      const uint4* qe4 = (const uint4*)(q_lds + 64 + hh*16);
      #pragma unroll
      for (int j4 = 0; j4 < 4; ++j4) {
        uint4 kw = kr4[j4];
        uint4 qw = qs4[j4];
        acc = fdot2(qw.x, kw.x, acc);
        acc = fdot2(qw.y, kw.y, acc);
        acc = fdot2(qw.z, kw.z, acc);
        acc = fdot2(qw.w, kw.w, acc);
      }
      const uint2* er = (const uint2*)(ebc + mq*18);
      #pragma unroll
      for (int j4 = 0; j4 < 4; ++j4) {
        uint4 qw = qe4[j4];
        uint2 w0 = er[2*j4], w1 = er[2*j4+1];
        acc = fdot2(qw.x, w0.x, acc);
        acc = fdot2(qw.y, w0.y, acc);
        acc = fdot2(qw.z, w1.x, acc);
        acc = fdot2(qw.w, w1.y, acc);
      }
      float mp = (c==0) ? mp0 : (c==1) ? mp1 : (c==2) ? mp2 : mp3;
      float ex = (mp == 0.0f) ? 0.0f : __expf(acc);   // no max-sub: |s| << 88
      s_chunk[c & 1][hh*66 + mq] = ex;
      exacc += ex;
    }

    // p3(c-1): register accumulation, wave-split (reads prev bufs)
    if (c > 0) {
      const unsigned int* ebp = e_buf + ((c-1) % 3)*64*18;
      const float* scp = s_chunk[(c-1) & 1];
      if (t < 128) {
        int e = t & 31, ht = t >> 5;
        const float* sc_ = scp + ht*66;
        const unsigned int* ebr = ebp + (e >> 1);
        bool hi = (e & 1);
        float a0 = 0.f, a1 = 0.f;
        #pragma unroll 8
        for (int m = 0; m < 64; m += 2) {
          float s0 = sc_[m], s1 = sc_[m+1];
          half2_t w0 = u2h(ebr[m*18]);
          half2_t w1 = u2h(ebr[(m+1)*18]);
          float e0 = hi ? (float)w0.y : (float)w0.x;
          float e1 = hi ? (float)w1.y : (float)w1.x;
          a0 += s0*e0; a1 += s1*e1;
        }
        acc4 += a0 + a1;
      } else {
        int idx = t - 128;
        int j = idx & 63, mh = idx >> 6;
        int head = j >> 4;
        const float* sc_ = scp + head*66 + mh*32;
        const unsigned int* vp = wsu + OFF_V0P + ((size_t)b*256 + (c-1)*64 + mh*32)*64 + j;
        float a0 = 0.f, a1 = 0.f;
        #pragma unroll 8
        for (int m = 0; m < 32; ++m) {
          float s = sc_[m];
          half2_t v = u2h(vp[(size_t)m*64]);
          a0 += s*(float)v.x; a1 += s*(float)v.y;
        }
        acc5x += a0; acc5y += a1;
      }
    }

    // stage chunk c+1 into buf (c+1)%3; issue loads for chunk c+2
    if (c < 3) {
      unsigned int* ebn = e_buf + ((c+1) % 3)*64*18;
      int lr = t >> 3, c4 = t & 7;
      uint2 pk;
      pk.x = pkf16(va.x, va.y); pk.y = pkf16(va.z, va.w);
      *(uint2*)(ebn + lr*18 + c4*2) = pk;
      uint2 pk2;
      pk2.x = pkf16(vb.x, vb.y); pk2.y = pkf16(vb.z, vb.w);
      *(uint2*)(ebn + (32 + lr)*18 + c4*2) = pk2;
      if (c < 2) {
        va = et[(c+2)*512 + t];
        vb = et[(c+2)*512 + 256 + t];
      }
    }
    __syncthreads();            // one barrier per chunk
  }

  // ---- exp-sum reduce (same-head lanes within wave) ----
  exacc += __shfl_down(exacc, 4);
  exacc += __shfl_down(exacc, 8);
  exacc += __shfl_down(exacc, 16);
  exacc += __shfl_down(exacc, 32);
  if ((t & 63) < 4) wpart[(t >> 6)*4 + hh] = exacc;

  // ---- p3(3): final chunk accumulation (after loop's last barrier) ----
  {
    const unsigned int* ebp = e_buf + (3 % 3)*64*18;
    const float* scp = s_chunk[1];
    if (t < 128) {
      int e = t & 31, ht = t >> 5;
      const float* sc_ = scp + ht*66;
      const unsigned int* ebr = ebp + (e >> 1);
      bool hi = (e & 1);
      float a0 = 0.f, a1 = 0.f;
      #pragma unroll 8
      for (int m = 0; m < 64; m += 2) {
        float s0 = sc_[m], s1 = sc_[m+1];
        half2_t w0 = u2h(ebr[m*18]);
        half2_t w1 = u2h(ebr[(m+1)*18]);
        float e0 = hi ? (float)w0.y : (float)w0.x;
        float e1 = hi ? (float)w1.y : (float)w1.x;
        a0 += s0*e0; a1 += s1*e1;
      }
      acc4 += a0 + a1;
    } else {
      int idx = t - 128;
      int j = idx & 63, mh = idx >> 6;
      int head = j >> 4;
      const float* sc_ = scp + head*66 + mh*32;
      const unsigned int* vp = wsu + OFF_V0P + ((size_t)b*256 + 192 + mh*32)*64 + j;
      float a0 = 0.f, a1 = 0.f;
      #pragma unroll 8
      for (int m = 0; m < 32; ++m) {
        float s = sc_[m];
        half2_t v = u2h(vp[(size_t)m*64]);
        a0 += s*(float)v.x; a1 += s*(float)v.y;
      }
      acc5x += a0; acc5y += a1;
    }
  }
  if (t >= 192) {                       // wave-3 ov partials -> LDS
    int j = (t - 128) & 63;
    float2 p; p.x = acc5x; p.y = acc5y;
    *(float2*)(ovh + j*2) = p;
  }
  __syncthreads();

  // ---- P4: normalize; ebar -> eb_l, ov (+vb) -> ov_l ----
  if (t < 128) {
    int ht = t >> 5;
    float inv = 1.0f / (wpart[ht] + wpart[4+ht] + wpart[8+ht] + wpart[12+ht]);
    eb_l[t] = acc4 * inv;
  } else if (t < 192) {
    int j = t - 128, head = j >> 4;
    float inv = 1.0f / (wpart[head] + wpart[4+head] + wpart[8+head] + wpart[12+head]);
    float2 oh = *(const float2*)(ovh + j*2);
    float2 res;
    res.x = (acc5x + oh.x)*inv + ws[OFF_VB + 2*j];
    res.y = (acc5y + oh.y)*inv + ws[OFF_VB + 2*j + 1];
    *(float2*)(ov_l + 2*j) = res;
  }
  __syncthreads();

  // ---- P5: o = ov + vb + WveT@ebar (t<128) ----
  if (t < 128) {
    int hd = t >> 5;
    float acc = ov_l[t];
    const float* wveT = ws + OFF_WVET;
    #pragma unroll 8
    for (int e = 0; e < 32; ++e) acc += wveT[e*128 + t] * eb_l[hd*32 + e];
    o_l[t] = acc;
  }
  __syncthreads();

  // ---- P6: out_w matvec, split-k over 2 halves (all 256 threads) ----
  {
    int d = t & 127, kh = t >> 7;
    const float* owT = ws + OFF_OWT;
    float xa = 0.f;
    #pragma unroll 8
    for (int kk = 0; kk < 64; ++kk) {
      int k = kh*64 + kk;
      xa += owT[k*128 + d] * o_l[k];
    }
    px[kh*128 + d] = xa;
  }
  __syncthreads();

  // ---- P7: residual + LN stats (t<128 holds x in reg) ----
  float x = 0.f;
  if (t < 128) {
    x = px[t] + px[128 + t] + out_b[t] + h_pre;
    float s = x, ss = x*x;
    #pragma unroll
    for (int off = 32; off > 0; off >>= 1) {
      s  += __shfl_down(s,  off);
      ss += __shfl_down(ss, off);
    }
    if ((t & 63) == 0) { stat[t >> 6] = s; stat[2 + (t >> 6)] = ss; }
  }
  __syncthreads();

  // ---- P8: LN + HG -> out ----
  if (t < 128) {
    float mu   = (stat[0] + stat[1]) * (1.0f/128.0f);
    float var  = (stat[2] + stat[3]) * (1.0f/128.0f) - mu*mu;
    float rstd = rsqrtf(var + 1e-5f);
    out[(size_t)bn*128 + t] =
        ln_g[t]*(x - mu)*rstd + ln_b[t] + hg_pre;
  }
}

// ---------------------------------------------------------------------------
extern "C" void kernel_launch(void* const* d_in, const int* in_sizes, int n_in,
                              void* d_out, int out_size, void* d_ws, size_t ws_size,
                              hipStream_t stream) {
  (void)in_sizes; (void)n_in; (void)out_size; (void)ws_size;
  const float* h     = (const float*)d_in[0];
  const float* adj   = (const float*)d_in[1];
  const float* edge  = (const float*)d_in[2];
  const float* srcm  = (const float*)d_in[3];
  const float* gcn_w = (const float*)d_in[4];
  const float* gcn_b = (const float*)d_in[5];
  const float* edge_w= (const float*)d_in[6];
  const float* edge_b= (const float*)d_in[7];
  const float* wq    = (const float*)d_in[8];
  const float* wk    = (const float*)d_in[9];
  const float* wv    = (const float*)d_in[10];
  const float* bq    = (const float*)d_in[11];
  const float* bk    = (const float*)d_in[12];
  const float* bv    = (const float*)d_in[13];
  const float* out_w = (const float*)d_in[14];
  const float* out_b = (const float*)d_in[15];
  const float* ln_g  = (const float*)d_in[16];
  const float* ln_b  = (const float*)d_in[17];

  float* ws  = (float*)d_ws;   // needs >= 3.6 MB
  float* out = (float*)d_out;

  prep_kernel<<<353, 256, 0, stream>>>(wq, wk, wv, out_w, gcn_w, edge_w, edge_b, bk, bv, ws);
  proj_kernel<<<1024, 256, 0, stream>>>(h, adj, bq, gcn_b, ws);
  attn_kernel<<<2048, 256, 0, stream>>>(edge, adj, srcm, h, out_b, ln_g, ln_b, ws, out);
}